// Round 4
// baseline (1685.105 us; speedup 1.0000x reference)
//
#include <hip/hip_runtime.h>

// ---------------------------------------------------------------------------
// NCEAverage forward, MI355X (gfx950) — restructured:
//   1. project ALL 81920 memory rows once (fused with the memory->out_mem copy)
//      projn[r] = l2norm(memory[r] @ W^T + bias)          (f32, 168 MB scratch)
//   2. out[b,k] = dot(projn[idx[b,k]], fp[b]) / T          (gather-dot, 1 wave/elem)
//   3. tail-copy the rows of out_mem that held projn/Wb/fp scratch
//   4. momentum scatter (last-wins) unchanged
// Scratch lives inside out_mem (no ws_size dependence):
//   projn = out_mem rows [    0, 20480)   (81920*512 f32 = 167.77 MB)
//   Wb    = out_mem rows [81648, 81904)   (512*2048 bf16 = 2 MB)
//   fp    = out_mem rows [81904, 81920)   (64*512 f32 = 128 KB)
// proj_all copy-writes rows [20480, 81648); tail_copy fills the rest after
// gather_dot has consumed projn/fp.
// ---------------------------------------------------------------------------

#define B_SZ     64
#define KP1      1024
#define D_IN     2048
#define D_PROJ   512
#define N_MEM    81920
#define INV_T    (1.0f / 0.07f)

// out_mem row ranges (rows of 2048 f32 = 8 KB)
#define PROJN_ROWS   20480              // projn occupies rows [0, 20480)
#define TAIL_ROW     81648              // Wb+fp occupy rows [81648, 81920)
#define TAIL_ROWS    272
#define COPY_SKIP    (TAIL_ROW - PROJN_ROWS)   // 61168

typedef __bf16 bf16x8 __attribute__((ext_vector_type(8)));
typedef float  f32x4  __attribute__((ext_vector_type(4)));

__device__ __forceinline__ unsigned short f2bf(float f) {
    unsigned int u = __float_as_uint(f);
    unsigned int r = (u + 0x7FFFu + ((u >> 16) & 1u)) >> 16;   // RTN-even
    return (unsigned short)r;
}

// --- kernel 0: W fp32 -> bf16 (1M elems) -----------------------------------
__global__ void cvt_w_kernel(const float* __restrict__ W, unsigned short* __restrict__ Wb) {
    int i = blockIdx.x * 256 + threadIdx.x;          // x4 floats
    float4 v = ((const float4*)W)[i];
    ushort4 o;
    o.x = f2bf(v.x); o.y = f2bf(v.y); o.z = f2bf(v.z); o.w = f2bf(v.w);
    ((ushort4*)Wb)[i] = o;
}

// --- kernel 1: feat_proj = l2norm(feat @ W^T + bias), fp32 -----------------
// grid 64 (one block per batch row), block 256
__global__ void feat_proj_kernel(const float* __restrict__ feat,
                                 const float* __restrict__ W,
                                 const float* __restrict__ bias,
                                 float* __restrict__ fp_out) {
    const int b = blockIdx.x, tid = threadIdx.x;
    __shared__ float sF[D_IN];
    __shared__ float sP[D_PROJ];
    __shared__ float sRed[256];

    #pragma unroll
    for (int i = 0; i < D_IN / 256; ++i)
        sF[tid + i * 256] = feat[(long)b * D_IN + tid + i * 256];
    __syncthreads();

    float pv[2];
    #pragma unroll
    for (int pass = 0; pass < 2; ++pass) {
        const int n = tid + pass * 256;
        const float4* wr = (const float4*)(W + (long)n * D_IN);
        const float4* fr = (const float4*)sF;
        float s = 0.f;
        for (int j = 0; j < D_IN / 4; ++j) {
            float4 wv = wr[j], fv = fr[j];
            s += wv.x * fv.x + wv.y * fv.y + wv.z * fv.z + wv.w * fv.w;
        }
        pv[pass] = s + bias[n];
        sP[n] = pv[pass];
    }
    __syncthreads();
    sRed[tid] = pv[0] * pv[0] + pv[1] * pv[1];
    __syncthreads();
    for (int s = 128; s > 0; s >>= 1) {
        if (tid < s) sRed[tid] += sRed[tid + s];
        __syncthreads();
    }
    const float rn = rsqrtf(sRed[0]);
    fp_out[(long)b * D_PROJ + tid]       = pv[0] * rn;
    fp_out[(long)b * D_PROJ + tid + 256] = pv[1] * rn;
}

// --- kernel 2: project ALL rows + fused copy -------------------------------
// grid 1280, block 256 (4 waves). Block handles 64 consecutive memory rows x
// all 512 cols. MFMA 16x16x32 bf16. Rows in [PROJN_ROWS, TAIL_ROW) are also
// copied f32 -> out_mem (the main memory copy, fused with the read).
#define AS_STRIDE 72   // 64 + 8 pad: row stride 144 B breaks 16-way bank conflict
__global__ __launch_bounds__(256, 2)
void proj_all_kernel(const float* __restrict__ memory,
                     const unsigned short* __restrict__ Wb,
                     const float* __restrict__ bias,
                     float* __restrict__ projn,
                     float* __restrict__ out_mem) {
    const int tid  = threadIdx.x;
    const int w    = tid >> 6;
    const int lane = tid & 63;
    const int quad = lane >> 4;
    const int c16  = lane & 15;
    const int r0   = blockIdx.x * 64;

    __shared__ unsigned short As[64 * AS_STRIDE];
    __shared__ float sBias[D_PROJ];
    __shared__ float sSS[4 * 64];
    __shared__ float sInv[64];

    for (int i = tid; i < D_PROJ; i += 256) sBias[i] = bias[i];

    f32x4 acc[4][8];
    const f32x4 zero = {0.f, 0.f, 0.f, 0.f};
    #pragma unroll
    for (int mt = 0; mt < 4; ++mt)
        #pragma unroll
        for (int nt = 0; nt < 8; ++nt) acc[mt][nt] = zero;

    const int  row  = tid >> 2;            // 0..63
    const int  q    = tid & 3;             // 16-float quarter of a 64-k slab
    const int  grow = r0 + row;
    const long arow = (long)grow * D_IN;
    const bool do_copy = (grow >= PROJN_ROWS) & (grow < TAIL_ROW);

    for (int k0 = 0; k0 < D_IN; k0 += 64) {
        // issue global loads early (before barrier)
        const float4* src = (const float4*)(memory + arow + k0 + q * 16);
        float4 v0 = src[0], v1 = src[1], v2 = src[2], v3 = src[3];
        if (do_copy) {
            float4* cdst = (float4*)(out_mem + arow + k0 + q * 16);
            cdst[0] = v0; cdst[1] = v1; cdst[2] = v2; cdst[3] = v3;
        }

        __syncthreads();   // prev tile's compute done
        float f[16] = {v0.x, v0.y, v0.z, v0.w, v1.x, v1.y, v1.z, v1.w,
                       v2.x, v2.y, v2.z, v2.w, v3.x, v3.y, v3.z, v3.w};
        unsigned int pk[8];
        #pragma unroll
        for (int j = 0; j < 8; ++j)
            pk[j] = (unsigned int)f2bf(f[2 * j]) | ((unsigned int)f2bf(f[2 * j + 1]) << 16);
        uint4* dst = (uint4*)&As[row * AS_STRIDE + q * 16];
        dst[0] = make_uint4(pk[0], pk[1], pk[2], pk[3]);
        dst[1] = make_uint4(pk[4], pk[5], pk[6], pk[7]);
        __syncthreads();   // As ready

        #pragma unroll
        for (int ks = 0; ks < 2; ++ks) {
            bf16x8 af[4];
            #pragma unroll
            for (int mt = 0; mt < 4; ++mt)
                af[mt] = *(const bf16x8*)&As[(mt * 16 + c16) * AS_STRIDE + ks * 32 + quad * 8];
            #pragma unroll
            for (int nt = 0; nt < 8; ++nt) {
                const int n = w * 128 + nt * 16 + c16;
                bf16x8 bfr = *(const bf16x8*)&Wb[(long)n * D_IN + k0 + ks * 32 + quad * 8];
                #pragma unroll
                for (int mt = 0; mt < 4; ++mt)
                    acc[mt][nt] = __builtin_amdgcn_mfma_f32_16x16x32_bf16(
                        af[mt], bfr, acc[mt][nt], 0, 0, 0);
            }
        }
    }

    // Epilogue: per-row sum(P^2) -> inv-norm -> write normalized rows (f32).
    // D layout: row-in-tile = quad*4 + r, col = c16.
    float ssl[4][4];
    #pragma unroll
    for (int mt = 0; mt < 4; ++mt)
        #pragma unroll
        for (int r = 0; r < 4; ++r) ssl[mt][r] = 0.f;

    #pragma unroll
    for (int nt = 0; nt < 8; ++nt) {
        const int n = w * 128 + nt * 16 + c16;
        const float bv = sBias[n];
        #pragma unroll
        for (int mt = 0; mt < 4; ++mt)
            #pragma unroll
            for (int r = 0; r < 4; ++r) {
                const float P = acc[mt][nt][r] + bv;
                ssl[mt][r] += P * P;
            }
    }
    #pragma unroll
    for (int off = 8; off >= 1; off >>= 1)
        #pragma unroll
        for (int mt = 0; mt < 4; ++mt)
            #pragma unroll
            for (int r = 0; r < 4; ++r)
                ssl[mt][r] += __shfl_xor(ssl[mt][r], off);
    if (c16 == 0) {
        #pragma unroll
        for (int mt = 0; mt < 4; ++mt)
            #pragma unroll
            for (int r = 0; r < 4; ++r)
                sSS[w * 64 + mt * 16 + quad * 4 + r] = ssl[mt][r];
    }
    __syncthreads();
    if (tid < 64)
        sInv[tid] = rsqrtf(sSS[tid] + sSS[64 + tid] + sSS[128 + tid] + sSS[192 + tid]);
    __syncthreads();

    #pragma unroll
    for (int mt = 0; mt < 4; ++mt)
        #pragma unroll
        for (int r = 0; r < 4; ++r) {
            const int  rr = mt * 16 + quad * 4 + r;
            const float iv = sInv[rr];
            const long base = (long)(r0 + rr) * D_PROJ;
            #pragma unroll
            for (int nt = 0; nt < 8; ++nt) {
                const int n = w * 128 + nt * 16 + c16;
                projn[base + n] = (acc[mt][nt][r] + sBias[n]) * iv;
            }
        }
}

// --- kernel 3: gather-dot: out[e] = dot(projn[idx[e]], fp[e>>10]) / T ------
// grid 16384, block 256 = 4 waves; one wave per output element (2 KB coalesced).
__global__ void gather_dot_kernel(const int* __restrict__ idx,
                                  const float* __restrict__ projn,
                                  const float* __restrict__ fp,
                                  float* __restrict__ out) {
    const int tid  = threadIdx.x;
    const int w    = tid >> 6;
    const int lane = tid & 63;
    const int e    = blockIdx.x * 4 + w;        // 0..65535
    const int b    = e >> 10;
    const int row  = idx[e];
    const float4* pr = (const float4*)(projn + (long)row * D_PROJ + lane * 8);
    const float4* fr = (const float4*)(fp    + (long)b   * D_PROJ + lane * 8);
    float4 p0 = pr[0], p1 = pr[1];
    float4 f0 = fr[0], f1 = fr[1];
    float s = p0.x * f0.x + p0.y * f0.y + p0.z * f0.z + p0.w * f0.w
            + p1.x * f1.x + p1.y * f1.y + p1.z * f1.z + p1.w * f1.w;
    #pragma unroll
    for (int off = 32; off >= 1; off >>= 1) s += __shfl_xor(s, off);
    if (lane == 0) out[e] = s * INV_T;
}

// --- kernel 4: copy the out_mem rows that held scratch ---------------------
// grid 20752 (one block per row: rows [0,20480) and [81648,81920)), block 256.
__global__ void tail_copy_kernel(const float4* __restrict__ src,
                                 float4* __restrict__ dst) {
    int r = blockIdx.x;                          // 0..20751
    int row = (r < PROJN_ROWS) ? r : r + COPY_SKIP;
    const long base = (long)row * (D_IN / 4);
    const int c = threadIdx.x;
    dst[base + c]       = src[base + c];
    dst[base + c + 256] = src[base + c + 256];
}

// --- kernel 5: momentum scatter update (last-wins) -------------------------
__global__ void scatter_kernel(const float* __restrict__ memory,
                               const float* __restrict__ feat,
                               const int* __restrict__ y,
                               float* __restrict__ out_mem) {
    const int i  = blockIdx.x;             // 0..63
    const int yi = y[i];
    for (int j = i + 1; j < B_SZ; ++j)
        if (y[j] == yi) return;            // a later write wins
    const float4* m4 = (const float4*)(memory + (long)yi * D_IN);
    const float4* f4 = (const float4*)(feat + (long)i * D_IN);
    float4* o4 = (float4*)(out_mem + (long)yi * D_IN);
    for (int c = threadIdx.x; c < D_IN / 4; c += 256) {
        float4 a = m4[c], b = f4[c];
        float4 r;
        r.x = 0.5f * (a.x + b.x); r.y = 0.5f * (a.y + b.y);
        r.z = 0.5f * (a.z + b.z); r.w = 0.5f * (a.w + b.w);
        o4[c] = r;
    }
}

extern "C" void kernel_launch(void* const* d_in, const int* in_sizes, int n_in,
                              void* d_out, int out_size, void* d_ws, size_t ws_size,
                              hipStream_t stream) {
    const float* feat   = (const float*)d_in[0];
    const int*   y      = (const int*)d_in[1];
    const int*   idx    = (const int*)d_in[2];
    const float* memory = (const float*)d_in[3];
    const float* W      = (const float*)d_in[4];
    const float* bias   = (const float*)d_in[5];

    float* out     = (float*)d_out;                 // [65536]
    float* out_mem = out + (long)B_SZ * KP1;        // [81920*2048]

    // Scratch inside out_mem (no ws_size dependence):
    float*          projn = out_mem;                                   // rows [0,20480)
    unsigned short* Wb    = (unsigned short*)(out_mem + (long)TAIL_ROW * D_IN); // 2 MB
    float*          fp    = out_mem + (long)TAIL_ROW * D_IN + (long)D_PROJ * D_IN / 2; // 128 KB

    cvt_w_kernel<<<(D_PROJ * D_IN) / (4 * 256), 256, 0, stream>>>(W, Wb);
    feat_proj_kernel<<<B_SZ, 256, 0, stream>>>(feat, W, bias, fp);
    proj_all_kernel<<<N_MEM / 64, 256, 0, stream>>>(memory, Wb, bias, projn, out_mem);
    gather_dot_kernel<<<(B_SZ * KP1) / 4, 256, 0, stream>>>(idx, projn, fp, out);
    tail_copy_kernel<<<PROJN_ROWS + TAIL_ROWS, 256, 0, stream>>>(
        (const float4*)memory, (float4*)out_mem);
    scatter_kernel<<<B_SZ, 256, 0, stream>>>(memory, feat, y, out_mem);
}